// Round 10
// baseline (237.222 us; speedup 1.0000x reference)
//
#include <hip/hip_runtime.h>

#define D_DIM 1024
#define NF 513            // rfft bins = D/2+1
#define NB 4              // batch
#define NS 2048           // sequence
#define NTOK (NB * NS)    // 8192 tokens
#define NCH 32            // cumsum chunks
#define CHS (NS / NCH)    // 64 steps per chunk

typedef __attribute__((ext_vector_type(8))) short short8_t;   // 8 bf16 = 4 VGPRs
typedef __attribute__((ext_vector_type(4))) float f32x4;

__device__ inline unsigned short f2bf(float f) {
    unsigned u = __builtin_bit_cast(unsigned, f);
    u += 0x7FFFu + ((u >> 16) & 1u);   // round-to-nearest-even
    return (unsigned short)(u >> 16);
}
__device__ inline float bf2f(unsigned short h) {
    unsigned u = ((unsigned)h) << 16;
    return __builtin_bit_cast(float, u);
}
__device__ inline unsigned pkc(float re, float im) {   // packed bf16 complex
    return (unsigned)f2bf(re) | ((unsigned)f2bf(im) << 16);
}
__device__ inline float2 upc(unsigned u) {
    return make_float2(bf2f((unsigned short)(u & 0xFFFFu)), bf2f((unsigned short)(u >> 16)));
}

__global__ __launch_bounds__(256) void convert_x(const float* __restrict__ src,
                                                 unsigned short* __restrict__ dst,
                                                 int n4) {
    int i = blockIdx.x * 256 + threadIdx.x;
    int stride = gridDim.x * 256;
    for (; i < n4; i += stride) {
        float4 v = reinterpret_cast<const float4*>(src)[i];
        ushort4 o;
        o.x = f2bf(v.x); o.y = f2bf(v.y); o.z = f2bf(v.z); o.w = f2bf(v.w);
        reinterpret_cast<ushort4*>(dst)[i] = o;
    }
}

// all four weights in one dispatch: gridDim.y selects the weight
__global__ __launch_bounds__(256) void convert_w(const float* __restrict__ Wq,
                                                 const float* __restrict__ Wk,
                                                 const float* __restrict__ Wv,
                                                 const float* __restrict__ Wo,
                                                 unsigned short* __restrict__ Wqkv,
                                                 unsigned short* __restrict__ Wob) {
    int y = blockIdx.y;
    const float* src = (y == 0) ? Wq : (y == 1) ? Wk : (y == 2) ? Wv : Wo;
    unsigned short* dst = (y < 3) ? (Wqkv + (size_t)y * 1048576) : Wob;
    int i = blockIdx.x * 256 + threadIdx.x;
    float4 v = reinterpret_cast<const float4*>(src)[i];
    ushort4 o;
    o.x = f2bf(v.x); o.y = f2bf(v.y); o.z = f2bf(v.z); o.w = f2bf(v.w);
    reinterpret_cast<ushort4*>(dst)[i] = o;
}

__device__ inline void gload_lds16(const void* g, void* l) {
    __builtin_amdgcn_global_load_lds(
        (const __attribute__((address_space(1))) void*)g,
        (__attribute__((address_space(3))) void*)l,
        16, 0, 0);
}

// ---------------------------------------------------------------------------
// bf16 MFMA GEMM: C[M,N] = A[M,K] * B[N,K]^T.  128x128 tile, BK=64, 4 waves
// of 64x64.  A staged in LDS (2-buffer, 32 KB, R9-proven swizzle); B read
// DIRECTLY global->VGPR per wave (L2-hot weights), double-buffered in two
// NAMED register banks (no runtime indexing), loop unrolled x2.
// vmcnt queue (order pinned by "memory" fences): [A(j)4, B(j)8, A(j+1)4,
// B(j+1)8] at round top -> vmcnt(20) == A(j) staged; tail vmcnt(8).
// B-register uses are compiler-tracked (C++ dataflow) -> safe waits.
// Requires NT = K/64 even.
// ---------------------------------------------------------------------------
template <typename OutT>
__global__ __launch_bounds__(256) void gemm_bf16_breg(const unsigned short* __restrict__ A,
                                                      const unsigned short* __restrict__ B,
                                                      OutT* __restrict__ C,
                                                      int M, int N, int K) {
    __shared__ __attribute__((aligned(16))) unsigned short ldsA[2 * 128 * 64];  // 32 KiB
    const int tid  = threadIdx.x;
    const int wave = tid >> 6;
    const int lane = tid & 63;
    const int l15  = lane & 15;
    const int q4   = (lane >> 4) & 3;
    const int h7   = l15 & 7;
    const int p0   = ((q4)     ^ h7) << 3;   // A read col offset, kk=0 (swizzled)
    const int p1   = ((4 + q4) ^ h7) << 3;   // kk=1
    const int wm   = (wave >> 1) * 64;
    const int wn   = (wave & 1) * 64;
    const int bm   = blockIdx.x * 128;
    const int bn   = blockIdx.y * 128;
    const int srow = tid >> 3;                              // 0..31
    const int scol = (((tid & 7) ^ ((tid >> 3) & 7)) << 3); // inverse-swizzled global col
    const int NT   = K >> 6;

    const unsigned short* Asrc = A + (size_t)(bm + srow) * K + scol;
    const size_t cstep = (size_t)32 * K;
    // B fragment base: lane reads row bn+wn+ni*16+l15, col k0 + kk*32 + q4*8
    const unsigned short* Bsrc = B + (size_t)(bn + wn + l15) * K + q4 * 8;

    f32x4 acc[4][4];
#pragma unroll
    for (int i = 0; i < 4; ++i)
#pragma unroll
        for (int j = 0; j < 4; ++j)
            acc[i][j] = (f32x4){0.f, 0.f, 0.f, 0.f};

    // STAGE_A(tile t -> buffer b): 4 global_load_lds per thread.
    auto STAGE_A = [&](int t, int b) {
        const int k0 = t << 6;
        unsigned short* la = &ldsA[b * 8192 + tid * 8];
        gload_lds16(Asrc + k0,             la);
        gload_lds16(Asrc + cstep + k0,     la + 2048);
        gload_lds16(Asrc + 2 * cstep + k0, la + 4096);
        gload_lds16(Asrc + 3 * cstep + k0, la + 6144);
    };
    // LOADB(tile t): 8 x dwordx4 global->reg.
    auto LOADB = [&](int t, short8_t (&bf)[2][4]) {
#pragma unroll
        for (int ni = 0; ni < 4; ++ni) {
            const unsigned short* p = Bsrc + (size_t)ni * 16 * K + (t << 6);
            bf[0][ni] = *reinterpret_cast<const short8_t*>(p);
            bf[1][ni] = *reinterpret_cast<const short8_t*>(p + 32);
        }
    };

    short8_t b0[2][4], b1[2][4];

    STAGE_A(0, 0);
    asm volatile("" ::: "memory");   // pin order: A(0) before B(0)
    LOADB(0, b0);
    asm volatile("" ::: "memory");

#define ROUND(J, BUF, BUSE, BNEXT)                                              \
    {                                                                           \
        const int j_ = (J);                                                     \
        if (j_ + 1 < NT) STAGE_A(j_ + 1, (BUF) ^ 1);                            \
        asm volatile("" ::: "memory");                                          \
        if (j_ + 1 < NT) LOADB(j_ + 1, BNEXT);                                  \
        if (j_ + 1 < NT) asm volatile("s_waitcnt vmcnt(20)" ::: "memory");      \
        else             asm volatile("s_waitcnt vmcnt(8)"  ::: "memory");      \
        __builtin_amdgcn_s_barrier();                                           \
        asm volatile("" ::: "memory");                                          \
        const unsigned short* la = &ldsA[(BUF) * 8192];                         \
        short8_t af[4];                                                         \
        _Pragma("unroll")                                                       \
        for (int mi = 0; mi < 4; ++mi)                                          \
            af[mi] = *reinterpret_cast<const short8_t*>(&la[(wm + mi * 16 + l15) * 64 + p0]); \
        __builtin_amdgcn_s_setprio(1);                                          \
        _Pragma("unroll")                                                       \
        for (int mi = 0; mi < 4; ++mi)                                          \
            _Pragma("unroll")                                                   \
            for (int ni = 0; ni < 4; ++ni)                                      \
                acc[mi][ni] = __builtin_amdgcn_mfma_f32_16x16x32_bf16(af[mi], BUSE[0][ni], acc[mi][ni], 0, 0, 0); \
        __builtin_amdgcn_s_setprio(0);                                          \
        _Pragma("unroll")                                                       \
        for (int mi = 0; mi < 4; ++mi)                                          \
            af[mi] = *reinterpret_cast<const short8_t*>(&la[(wm + mi * 16 + l15) * 64 + p1]); \
        __builtin_amdgcn_s_setprio(1);                                          \
        _Pragma("unroll")                                                       \
        for (int mi = 0; mi < 4; ++mi)                                          \
            _Pragma("unroll")                                                   \
            for (int ni = 0; ni < 4; ++ni)                                      \
                acc[mi][ni] = __builtin_amdgcn_mfma_f32_16x16x32_bf16(af[mi], BUSE[1][ni], acc[mi][ni], 0, 0, 0); \
        __builtin_amdgcn_s_setprio(0);                                          \
        __builtin_amdgcn_s_barrier();                                           \
        asm volatile("" ::: "memory");                                          \
    }

    for (int jj = 0; jj < NT; jj += 2) {
        ROUND(jj,     0, b0, b1)
        ROUND(jj + 1, 1, b1, b0)
    }
#undef ROUND

#pragma unroll
    for (int mi = 0; mi < 4; ++mi) {
        int rbase = bm + wm + mi * 16 + (lane >> 4) * 4;
#pragma unroll
        for (int ni = 0; ni < 4; ++ni) {
            int col = bn + wn + ni * 16 + l15;
#pragma unroll
            for (int j = 0; j < 4; ++j) {
                float v = acc[mi][ni][j];
                if constexpr (sizeof(OutT) == 4)
                    C[(size_t)(rbase + j) * N + col] = v;
                else
                    C[(size_t)(rbase + j) * N + col] = f2bf(v);
            }
        }
    }
}

// ---------------------------------------------------------------------------
// Radix-4 1024-pt complex FFT in LDS, float2 elements, XOR bank swizzle.
// ---------------------------------------------------------------------------
__device__ inline int sw(int i) { return i ^ ((i >> 4) & 15); }

__device__ inline int dr4(int n) {   // reverse 5 base-4 digits of 10-bit n
    return ((n & 3) << 8) | (((n >> 2) & 3) << 6) | (((n >> 4) & 3) << 4) |
           (((n >> 6) & 3) << 2) | ((n >> 8) & 3);
}

__device__ inline float2 cmul(float2 a, float2 b) {
    return make_float2(a.x * b.x - a.y * b.y, a.x * b.y + a.y * b.x);
}

__device__ inline void fft1024_r4(float2* X, const float2* tw, int t) {
#pragma unroll
    for (int s = 0; s < 5; ++s) {
        const int L = 1 << (2 * s);
        const int r = t & (L - 1);
        const int base = ((t >> (2 * s)) << (2 * s + 2)) + r;
        float2 A  = X[sw(base)];
        float2 Bv = X[sw(base + L)];
        float2 Cv = X[sw(base + 2 * L)];
        float2 Dv = X[sw(base + 3 * L)];
        if (s != 0) {
            const int step = 1024 >> (2 * s + 2);
            Bv = cmul(Bv, tw[sw(r * step)]);
            Cv = cmul(Cv, tw[sw(2 * r * step)]);
            Dv = cmul(Dv, tw[sw(3 * r * step)]);
        }
        float2 e0 = make_float2(A.x + Cv.x, A.y + Cv.y);
        float2 e1 = make_float2(A.x - Cv.x, A.y - Cv.y);
        float2 o0 = make_float2(Bv.x + Dv.x, Bv.y + Dv.y);
        float2 o1 = make_float2(Bv.x - Dv.x, Bv.y - Dv.y);
        X[sw(base)]         = make_float2(e0.x + o0.x, e0.y + o0.y);
        X[sw(base + L)]     = make_float2(e1.x + o1.y, e1.y - o1.x);
        X[sw(base + 2 * L)] = make_float2(e0.x - o0.x, e0.y - o0.y);
        X[sw(base + 3 * L)] = make_float2(e1.x - o1.y, e1.y + o1.x);
        __syncthreads();
    }
}

__global__ __launch_bounds__(256) void twiddle_init(float2* __restrict__ twg) {
    int k = blockIdx.x * 256 + threadIdx.x;
    if (k < 768) {
        float ang = -6.283185307179586f * (float)k / 1024.0f;
        float s, c;
        sincosf(ang, &s, &c);
        twg[sw(k)] = make_float2(c, s);
    }
}

// ---------------------------------------------------------------------------
// Forward: block handles tokens (2b, 2b+1). QKV is bf16 [tok][3072] = q|k|v.
// ---------------------------------------------------------------------------
__global__ __launch_bounds__(256) void hrr_fft_fwd(const unsigned short* __restrict__ QKV,
                                                   const float2* __restrict__ twg,
                                                   unsigned* __restrict__ Fkv,
                                                   unsigned* __restrict__ Fq) {
    __shared__ __attribute__((aligned(16))) float2 X[1024];
    __shared__ __attribute__((aligned(16))) float2 twL[768];
    const int tid = threadIdx.x;
    const int t0 = blockIdx.x * 2, t1 = t0 + 1;
    for (int i = tid; i < 384; i += 256)
        reinterpret_cast<float4*>(twL)[i] = reinterpret_cast<const float4*>(twg)[i];

#pragma unroll
    for (int which = 0; which < 2; ++which) {
        const int tok = which ? t1 : t0;
        const ushort4* Kr = (const ushort4*)(QKV + (size_t)tok * 3072 + 1024);
        const ushort4* Vr = (const ushort4*)(QKV + (size_t)tok * 3072 + 2048);
        ushort4 k4 = Kr[tid], v4 = Vr[tid];
        X[sw(dr4(4 * tid + 0))] = make_float2(bf2f(k4.x), bf2f(v4.x));
        X[sw(dr4(4 * tid + 1))] = make_float2(bf2f(k4.y), bf2f(v4.y));
        X[sw(dr4(4 * tid + 2))] = make_float2(bf2f(k4.z), bf2f(v4.z));
        X[sw(dr4(4 * tid + 3))] = make_float2(bf2f(k4.w), bf2f(v4.w));
        __syncthreads();
        fft1024_r4(X, twL, tid);
        for (int j = tid; j < NF; j += 256) {
            float2 Zj = X[sw(j)];
            float2 Zm = X[sw((1024 - j) & 1023)];
            float2 Fk = make_float2(0.5f * (Zj.x + Zm.x), 0.5f * (Zj.y - Zm.y));
            float2 Fv = make_float2(0.5f * (Zj.y + Zm.y), 0.5f * (Zm.x - Zj.x));
            float2 p = cmul(Fk, Fv);
            Fkv[(size_t)tok * NF + j] = pkc(p.x, p.y);
        }
        __syncthreads();
    }
    // Q pair
    {
        const ushort4* Q0 = (const ushort4*)(QKV + (size_t)t0 * 3072);
        const ushort4* Q1 = (const ushort4*)(QKV + (size_t)t1 * 3072);
        ushort4 a4 = Q0[tid], b4 = Q1[tid];
        X[sw(dr4(4 * tid + 0))] = make_float2(bf2f(a4.x), bf2f(b4.x));
        X[sw(dr4(4 * tid + 1))] = make_float2(bf2f(a4.y), bf2f(b4.y));
        X[sw(dr4(4 * tid + 2))] = make_float2(bf2f(a4.z), bf2f(b4.z));
        X[sw(dr4(4 * tid + 3))] = make_float2(bf2f(a4.w), bf2f(b4.w));
        __syncthreads();
        fft1024_r4(X, twL, tid);
        for (int j = tid; j < NF; j += 256) {
            float2 Zj = X[sw(j)];
            float2 Zm = X[sw((1024 - j) & 1023)];
            Fq[(size_t)t0 * NF + j] = pkc(0.5f * (Zj.x + Zm.x), 0.5f * (Zj.y - Zm.y));
            Fq[(size_t)t1 * NF + j] = pkc(0.5f * (Zj.y + Zm.y), 0.5f * (Zm.x - Zj.x));
        }
    }
}

// ---------------------------------------------------------------------------
// Chunked causal cumsum (fp32 accumulation over bf16 terms).
// ---------------------------------------------------------------------------
__global__ __launch_bounds__(256) void hrr_chunk_sum(const unsigned* __restrict__ Fkv,
                                                     float2* __restrict__ part) {
    int f = blockIdx.x * 256 + threadIdx.x;
    if (f >= NF) return;
    int ch = blockIdx.y, b = blockIdx.z;
    float sx = 0.f, sy = 0.f;
    size_t base = ((size_t)b * NS + (size_t)ch * CHS) * NF + f;
    for (int i = 0; i < CHS; ++i) {
        float2 t = upc(Fkv[base + (size_t)i * NF]);
        sx += t.x; sy += t.y;
    }
    part[(size_t)(b * NCH + ch) * NF + f] = make_float2(sx, sy);
}

__global__ __launch_bounds__(256) void hrr_scan_apply(unsigned* __restrict__ Fkv,
                                                      const unsigned* __restrict__ Fq,
                                                      const float2* __restrict__ part) {
    int f = blockIdx.x * 256 + threadIdx.x;
    if (f >= NF) return;
    int ch = blockIdx.y, b = blockIdx.z;
    float rx = 0.f, ry = 0.f;
    for (int c2 = 0; c2 < ch; ++c2) {
        float2 p = part[(size_t)(b * NCH + c2) * NF + f];
        rx += p.x; ry += p.y;
    }
    size_t base = ((size_t)b * NS + (size_t)ch * CHS) * NF + f;
    for (int i = 0; i < CHS; ++i) {
        size_t idx = base + (size_t)i * NF;
        float2 kv = upc(Fkv[idx]);
        rx += kv.x; ry += kv.y;
        float2 q = upc(Fq[idx]);
        Fkv[idx] = pkc(rx * q.x + ry * q.y, ry * q.x - rx * q.y);
    }
}

// ---------------------------------------------------------------------------
// Paired irfft of bf16 U; writes vhat bf16.
// ---------------------------------------------------------------------------
__global__ __launch_bounds__(256) void hrr_ifft(const unsigned* __restrict__ U,
                                                const float2* __restrict__ twg,
                                                unsigned short* __restrict__ vhat) {
    __shared__ __attribute__((aligned(16))) float2 X[1024];
    __shared__ __attribute__((aligned(16))) float2 twL[768];
    const int tid = threadIdx.x;
    const int t0 = blockIdx.x * 2, t1 = t0 + 1;
    for (int i = tid; i < 384; i += 256)
        reinterpret_cast<float4*>(twL)[i] = reinterpret_cast<const float4*>(twg)[i];
    const unsigned* U1 = U + (size_t)t0 * NF;
    const unsigned* U2 = U + (size_t)t1 * NF;
#pragma unroll
    for (int c = 0; c < 4; ++c) {
        int j = tid + (c << 8);
        float2 Cv;
        if (j <= 512) {
            float2 u1 = upc(U1[j]), u2 = upc(U2[j]);
            Cv = make_float2(u1.x - u2.y, -u1.y - u2.x);
        } else {
            int m = 1024 - j;
            float2 u1 = upc(U1[m]), u2 = upc(U2[m]);
            Cv = make_float2(u1.x + u2.y, u1.y - u2.x);
        }
        X[sw(dr4(j))] = Cv;
    }
    __syncthreads();
    fft1024_r4(X, twL, tid);
    const float invN = 1.0f / 1024.0f;
#pragma unroll
    for (int c = 0; c < 4; ++c) {
        int n = tid + (c << 8);
        float2 w = X[sw(n)];
        vhat[(size_t)t0 * D_DIM + n] = f2bf(w.x * invN);
        vhat[(size_t)t1 * D_DIM + n] = f2bf(-w.y * invN);
    }
}

// ---------------------------------------------------------------------------
extern "C" void kernel_launch(void* const* d_in, const int* in_sizes, int n_in,
                              void* d_out, int out_size, void* d_ws, size_t ws_size,
                              hipStream_t stream) {
    const float* x  = (const float*)d_in[0];
    const float* Wq = (const float*)d_in[1];
    const float* Wk = (const float*)d_in[2];
    const float* Wv = (const float*)d_in[3];
    const float* Wo = (const float*)d_in[4];
    float* out = (float*)d_out;

    char* ws = (char*)d_ws;
    unsigned short* QKVb = (unsigned short*)(ws + 0);          // 50,331,648 B
    unsigned*       Fkv  = (unsigned*)      (ws + 50331648);   // 16,809,984 B
    unsigned*       Fq   = (unsigned*)      (ws + 67141632);   // 16,809,984 B
    float2*         part = (float2*)        (ws + 83951616);   //    525,312 B
    float2*         twg  = (float2*)        (ws + 84476928);   //      6,144 B
    unsigned short* Wob  = (unsigned short*)(ws + 84483072);   //  2,097,152 B
    unsigned short* Wqkv = (unsigned short*)(ws + 86580224);   //  6,291,456 B
    unsigned short* xb   = (unsigned short*)(ws + 92871680);   // 16,777,216 B
    unsigned short* vhat = (unsigned short*)(ws + 109648896);  // 16,777,216 B (end ~126.4 MB)

    convert_x<<<2048, 256, 0, stream>>>(x, xb, NTOK * D_DIM / 4);
    convert_w<<<dim3(1024, 4), 256, 0, stream>>>(Wq, Wk, Wv, Wo, Wqkv, Wob);
    twiddle_init<<<3, 256, 0, stream>>>(twg);

    dim3 gq(NTOK / 128, 3072 / 128);
    gemm_bf16_breg<unsigned short><<<gq, 256, 0, stream>>>(xb, Wqkv, QKVb, NTOK, 3072, D_DIM);

    hrr_fft_fwd<<<NTOK / 2, 256, 0, stream>>>(QKVb, twg, Fkv, Fq);

    dim3 gs((NF + 255) / 256, NCH, NB);
    hrr_chunk_sum<<<gs, 256, 0, stream>>>(Fkv, part);
    hrr_scan_apply<<<gs, 256, 0, stream>>>(Fkv, Fq, part);

    hrr_ifft<<<NTOK / 2, 256, 0, stream>>>(Fkv, twg, vhat);

    dim3 go(NTOK / 128, D_DIM / 128);
    gemm_bf16_breg<float><<<go, 256, 0, stream>>>(vhat, Wob, out, NTOK, D_DIM, D_DIM);
}

// Round 11
// 191.264 us; speedup vs baseline: 1.2403x; 1.2403x over previous
//
#include <hip/hip_runtime.h>
#include <hip/hip_fp16.h>

#define D_DIM 1024
#define NF 513            // rfft bins = D/2+1
#define NB 4              // batch
#define NS 2048           // sequence
#define NTOK (NB * NS)    // 8192 tokens
#define NCH 32            // cumsum chunks
#define CHS (NS / NCH)    // 64 steps per chunk
#define NQKV 3200         // 3*1026 freq-interleaved rows, padded to 128-multiple
#define KOUT 1088         // 1026 padded to 64-multiple
#define USTRIDE 544       // KOUT/2 (packed complex per row)

typedef __attribute__((ext_vector_type(8))) short short8_t;   // 8 bf16 = 4 VGPRs
typedef __attribute__((ext_vector_type(4))) float f32x4;

__device__ inline unsigned short f2bf(float f) {
    unsigned u = __builtin_bit_cast(unsigned, f);
    u += 0x7FFFu + ((u >> 16) & 1u);   // round-to-nearest-even
    return (unsigned short)(u >> 16);
}
__device__ inline float bf2f(unsigned short h) {
    unsigned u = ((unsigned)h) << 16;
    return __builtin_bit_cast(float, u);
}
__device__ inline unsigned pkc(float re, float im) {   // packed bf16 complex
    return (unsigned)f2bf(re) | ((unsigned)f2bf(im) << 16);
}
// packed fp16 complex
__device__ inline float2 uph(unsigned u) {
    unsigned short lo = (unsigned short)(u & 0xFFFFu), hi = (unsigned short)(u >> 16);
    return make_float2(__half2float(__builtin_bit_cast(__half, lo)),
                       __half2float(__builtin_bit_cast(__half, hi)));
}

__global__ __launch_bounds__(256) void convert_x(const float* __restrict__ src,
                                                 unsigned short* __restrict__ dst,
                                                 int n4) {
    int i = blockIdx.x * 256 + threadIdx.x;
    int stride = gridDim.x * 256;
    for (; i < n4; i += stride) {
        float4 v = reinterpret_cast<const float4*>(src)[i];
        ushort4 o;
        o.x = f2bf(v.x); o.y = f2bf(v.y); o.z = f2bf(v.z); o.w = f2bf(v.w);
        reinterpret_cast<ushort4*>(dst)[i] = o;
    }
}

__device__ inline void gload_lds16(const void* g, void* l) {
    __builtin_amdgcn_global_load_lds(
        (const __attribute__((address_space(1))) void*)g,
        (__attribute__((address_space(3))) void*)l,
        16, 0, 0);
}

// ---------------------------------------------------------------------------
// R9-proven bf16 MFMA GEMM: 128x128 tile, BK=64, 4 waves of 64x64, 2-buffer
// LDS (64 KB), counted vmcnt(8)/0, raw barriers, bank swizzle both-sides.
// F16OUT selects fp16 vs bf16 epilogue for 2-byte outputs.
// ---------------------------------------------------------------------------
template <typename OutT, bool F16OUT>
__global__ __launch_bounds__(256) void gemm_bf16_bk64(const unsigned short* __restrict__ A,
                                                      const unsigned short* __restrict__ B,
                                                      OutT* __restrict__ C,
                                                      int M, int N, int K) {
    __shared__ __attribute__((aligned(16))) unsigned short ldsA[2 * 128 * 64];  // 32 KiB
    __shared__ __attribute__((aligned(16))) unsigned short ldsB[2 * 128 * 64];  // 32 KiB
    const int tid  = threadIdx.x;
    const int wave = tid >> 6;
    const int lane = tid & 63;
    const int l15  = lane & 15;
    const int q4   = (lane >> 4) & 3;
    const int h7   = l15 & 7;
    const int p0   = ((q4)     ^ h7) << 3;
    const int p1   = ((4 + q4) ^ h7) << 3;
    const int wm   = (wave >> 1) * 64;
    const int wn   = (wave & 1) * 64;
    const int bm   = blockIdx.x * 128;
    const int bn   = blockIdx.y * 128;
    const int srow = tid >> 3;
    const int scol = (((tid & 7) ^ ((tid >> 3) & 7)) << 3);
    const int NT   = K >> 6;

    const unsigned short* Asrc = A + (size_t)(bm + srow) * K + scol;
    const unsigned short* Bsrc = B + (size_t)(bn + srow) * K + scol;
    const size_t cstep = (size_t)32 * K;

    f32x4 acc[4][4];
#pragma unroll
    for (int i = 0; i < 4; ++i)
#pragma unroll
        for (int j = 0; j < 4; ++j)
            acc[i][j] = (f32x4){0.f, 0.f, 0.f, 0.f};

    auto STAGE = [&](int t, int b) {
        const int k0 = t << 6;
        unsigned short* la = &ldsA[b * 8192 + tid * 8];
        unsigned short* lb = &ldsB[b * 8192 + tid * 8];
        gload_lds16(Asrc + k0,             la);
        gload_lds16(Asrc + cstep + k0,     la + 2048);
        gload_lds16(Asrc + 2 * cstep + k0, la + 4096);
        gload_lds16(Asrc + 3 * cstep + k0, la + 6144);
        gload_lds16(Bsrc + k0,             lb);
        gload_lds16(Bsrc + cstep + k0,     lb + 2048);
        gload_lds16(Bsrc + 2 * cstep + k0, lb + 4096);
        gload_lds16(Bsrc + 3 * cstep + k0, lb + 6144);
    };

    STAGE(0, 0);

    for (int j = 0; j < NT; ++j) {
        const int buf = j & 1;
        if (j + 1 < NT) {
            STAGE(j + 1, buf ^ 1);
            asm volatile("s_waitcnt vmcnt(8)" ::: "memory");
        } else {
            asm volatile("s_waitcnt vmcnt(0)" ::: "memory");
        }
        __builtin_amdgcn_s_barrier();
        asm volatile("" ::: "memory");

        const unsigned short* la = &ldsA[buf * 8192];
        const unsigned short* lb = &ldsB[buf * 8192];

        {
            short8_t af[4], bfv[4];
#pragma unroll
            for (int mi = 0; mi < 4; ++mi)
                af[mi] = *reinterpret_cast<const short8_t*>(&la[(wm + mi * 16 + l15) * 64 + p0]);
#pragma unroll
            for (int ni = 0; ni < 4; ++ni)
                bfv[ni] = *reinterpret_cast<const short8_t*>(&lb[(wn + ni * 16 + l15) * 64 + p0]);
            __builtin_amdgcn_s_setprio(1);
#pragma unroll
            for (int mi = 0; mi < 4; ++mi)
#pragma unroll
                for (int ni = 0; ni < 4; ++ni)
                    acc[mi][ni] = __builtin_amdgcn_mfma_f32_16x16x32_bf16(af[mi], bfv[ni], acc[mi][ni], 0, 0, 0);
            __builtin_amdgcn_s_setprio(0);
        }
        {
            short8_t af[4], bfv[4];
#pragma unroll
            for (int mi = 0; mi < 4; ++mi)
                af[mi] = *reinterpret_cast<const short8_t*>(&la[(wm + mi * 16 + l15) * 64 + p1]);
#pragma unroll
            for (int ni = 0; ni < 4; ++ni)
                bfv[ni] = *reinterpret_cast<const short8_t*>(&lb[(wn + ni * 16 + l15) * 64 + p1]);
            __builtin_amdgcn_s_setprio(1);
#pragma unroll
            for (int mi = 0; mi < 4; ++mi)
#pragma unroll
                for (int ni = 0; ni < 4; ++ni)
                    acc[mi][ni] = __builtin_amdgcn_mfma_f32_16x16x32_bf16(af[mi], bfv[ni], acc[mi][ni], 0, 0, 0);
            __builtin_amdgcn_s_setprio(0);
        }

        __builtin_amdgcn_s_barrier();
        asm volatile("" ::: "memory");
    }

#pragma unroll
    for (int mi = 0; mi < 4; ++mi) {
        int rbase = bm + wm + mi * 16 + (lane >> 4) * 4;
#pragma unroll
        for (int ni = 0; ni < 4; ++ni) {
            int col = bn + wn + ni * 16 + l15;
#pragma unroll
            for (int j = 0; j < 4; ++j) {
                float v = acc[mi][ni][j];
                if constexpr (sizeof(OutT) == 4)
                    C[(size_t)(rbase + j) * N + col] = v;
                else if constexpr (F16OUT)
                    C[(size_t)(rbase + j) * N + col] =
                        __builtin_bit_cast(unsigned short, __float2half(v));
                else
                    C[(size_t)(rbase + j) * N + col] = f2bf(v);
            }
        }
    }
}

// ---------------------------------------------------------------------------
// Radix-4 1024-pt complex FFT in LDS (proven): XOR bank swizzle, digit-rev.
// ---------------------------------------------------------------------------
__device__ inline int sw(int i) { return i ^ ((i >> 4) & 15); }

__device__ inline int dr4(int n) {
    return ((n & 3) << 8) | (((n >> 2) & 3) << 6) | (((n >> 4) & 3) << 4) |
           (((n >> 6) & 3) << 2) | ((n >> 8) & 3);
}

__device__ inline float2 cmul(float2 a, float2 b) {
    return make_float2(a.x * b.x - a.y * b.y, a.x * b.y + a.y * b.x);
}

__device__ inline void fft1024_r4(float2* X, const float2* tw, int t) {
#pragma unroll
    for (int s = 0; s < 5; ++s) {
        const int L = 1 << (2 * s);
        const int r = t & (L - 1);
        const int base = ((t >> (2 * s)) << (2 * s + 2)) + r;
        float2 A  = X[sw(base)];
        float2 Bv = X[sw(base + L)];
        float2 Cv = X[sw(base + 2 * L)];
        float2 Dv = X[sw(base + 3 * L)];
        if (s != 0) {
            const int step = 1024 >> (2 * s + 2);
            Bv = cmul(Bv, tw[sw(r * step)]);
            Cv = cmul(Cv, tw[sw(2 * r * step)]);
            Dv = cmul(Dv, tw[sw(3 * r * step)]);
        }
        float2 e0 = make_float2(A.x + Cv.x, A.y + Cv.y);
        float2 e1 = make_float2(A.x - Cv.x, A.y - Cv.y);
        float2 o0 = make_float2(Bv.x + Dv.x, Bv.y + Dv.y);
        float2 o1 = make_float2(Bv.x - Dv.x, Bv.y - Dv.y);
        X[sw(base)]         = make_float2(e0.x + o0.x, e0.y + o0.y);
        X[sw(base + L)]     = make_float2(e1.x + o1.y, e1.y - o1.x);
        X[sw(base + 2 * L)] = make_float2(e0.x - o0.x, e0.y - o0.y);
        X[sw(base + 3 * L)] = make_float2(e1.x - o1.y, e1.y + o1.x);
        __syncthreads();
    }
}

__global__ __launch_bounds__(256) void twiddle_init(float2* __restrict__ twg) {
    int k = blockIdx.x * 256 + threadIdx.x;
    if (k < 768) {
        float ang = -6.283185307179586f * (float)k / 1024.0f;
        float s, c;
        sincosf(ang, &s, &c);
        twg[sw(k)] = make_float2(c, s);
    }
}

// ---------------------------------------------------------------------------
// Weight-FFT preprocessing, QKV side: WF[3200][1024] bf16.
// Row 2f (+w*1026) = Re(FFT over e of W[e][d])[f], row 2f+1 = Im.
// Two columns (d0, d0+1) per block via one complex FFT + untangle.
// ---------------------------------------------------------------------------
__global__ __launch_bounds__(256) void wf_qkv(const float* __restrict__ Wq,
                                              const float* __restrict__ Wk,
                                              const float* __restrict__ Wv,
                                              const float2* __restrict__ twg,
                                              unsigned short* __restrict__ WF) {
    __shared__ __attribute__((aligned(16))) float2 X[1024];
    __shared__ __attribute__((aligned(16))) float2 twL[768];
    const int tid = threadIdx.x;
    const int w = blockIdx.y;
    const float* W = (w == 0) ? Wq : (w == 1) ? Wk : Wv;
    const int d0 = blockIdx.x * 2;
    for (int i = tid; i < 384; i += 256)
        reinterpret_cast<float4*>(twL)[i] = reinterpret_cast<const float4*>(twg)[i];
    for (int n = tid; n < 1024; n += 256) {
        float2 z = *reinterpret_cast<const float2*>(W + (size_t)n * 1024 + d0);
        X[sw(dr4(n))] = z;
    }
    __syncthreads();
    fft1024_r4(X, twL, tid);
    const int rbase = w * 1026;
    for (int f = tid; f < NF; f += 256) {
        float2 Zj = X[sw(f)];
        float2 Zm = X[sw((1024 - f) & 1023)];
        float re0 = 0.5f * (Zj.x + Zm.x), im0 = 0.5f * (Zj.y - Zm.y);
        float re1 = 0.5f * (Zj.y + Zm.y), im1 = 0.5f * (Zm.x - Zj.x);
        WF[(size_t)(rbase + 2 * f)     * 1024 + d0]     = f2bf(re0);
        WF[(size_t)(rbase + 2 * f + 1) * 1024 + d0]     = f2bf(im0);
        WF[(size_t)(rbase + 2 * f)     * 1024 + d0 + 1] = f2bf(re1);
        WF[(size_t)(rbase + 2 * f + 1) * 1024 + d0 + 1] = f2bf(im1);
    }
}

__global__ __launch_bounds__(256) void wf_zero(unsigned* __restrict__ p) {
    // zero WF rows 3078..3199: 122*1024 bf16 = 62464 uints
    int i = blockIdx.x * 256 + threadIdx.x;
    if (i < 62464) p[i] = 0;
}

// ---------------------------------------------------------------------------
// Weight-FFT preprocessing, Wo side (Parseval): Wt[1024][1088] bf16.
// Wt[e][2f] = c_f*Re(rfft(Wo[e,:]))[f]/1024, [2f+1] = c_f*Im/1024; pad cols 0.
// Two rows (e0, e0+1) per block; coalesced loads + stores.
// ---------------------------------------------------------------------------
__global__ __launch_bounds__(256) void wf_o(const float* __restrict__ Wo,
                                            const float2* __restrict__ twg,
                                            unsigned short* __restrict__ Wt) {
    __shared__ __attribute__((aligned(16))) float2 X[1024];
    __shared__ __attribute__((aligned(16))) float2 twL[768];
    const int tid = threadIdx.x;
    const int e0 = blockIdx.x * 2;
    for (int i = tid; i < 384; i += 256)
        reinterpret_cast<float4*>(twL)[i] = reinterpret_cast<const float4*>(twg)[i];
    const float* r0 = Wo + (size_t)e0 * 1024;
    const float* r1 = r0 + 1024;
    for (int n = tid; n < 1024; n += 256)
        X[sw(dr4(n))] = make_float2(r0[n], r1[n]);
    __syncthreads();
    fft1024_r4(X, twL, tid);
    unsigned short* o0 = Wt + (size_t)e0 * KOUT;
    unsigned short* o1 = o0 + KOUT;
    for (int f = tid; f < NF; f += 256) {
        float2 Zj = X[sw(f)];
        float2 Zm = X[sw((1024 - f) & 1023)];
        float c = (f == 0 || f == 512) ? (1.0f / 1024.0f) : (2.0f / 1024.0f);
        o0[2 * f]     = f2bf(0.5f * (Zj.x + Zm.x) * c);
        o0[2 * f + 1] = f2bf(0.5f * (Zj.y - Zm.y) * c);
        o1[2 * f]     = f2bf(0.5f * (Zj.y + Zm.y) * c);
        o1[2 * f + 1] = f2bf(0.5f * (Zm.x - Zj.x) * c);
    }
    for (int j = tid; j < KOUT - 2 * NF; j += 256) {   // pad cols 1026..1087
        o0[2 * NF + j] = 0;
        o1[2 * NF + j] = 0;
    }
}

// ---------------------------------------------------------------------------
// Scans over F_all [8192][1600] packed fp16 complex (Fq | Fk | Fv per row).
// Fkv product recomputed in fp32 from fp16 Fk,Fv (never materialized).
// ---------------------------------------------------------------------------
__global__ __launch_bounds__(256) void hrr_chunk_sum(const unsigned* __restrict__ F,
                                                     float2* __restrict__ part) {
    int f = blockIdx.x * 256 + threadIdx.x;
    if (f >= NF) return;
    int ch = blockIdx.y, b = blockIdx.z;
    float sx = 0.f, sy = 0.f;
    size_t base = ((size_t)b * NS + (size_t)ch * CHS) * 1600;
    for (int i = 0; i < CHS; ++i) {
        size_t row = base + (size_t)i * 1600;
        float2 k = uph(F[row + 513 + f]);
        float2 v = uph(F[row + 1026 + f]);
        sx += k.x * v.x - k.y * v.y;
        sy += k.x * v.y + k.y * v.x;
    }
    part[(size_t)(b * NCH + ch) * NF + f] = make_float2(sx, sy);
}

__global__ __launch_bounds__(256) void hrr_scan_apply(const unsigned* __restrict__ F,
                                                      const float2* __restrict__ part,
                                                      unsigned* __restrict__ U) {
    int f = blockIdx.x * 256 + threadIdx.x;
    if (f >= USTRIDE) return;
    int ch = blockIdx.y, b = blockIdx.z;
    size_t ubase = ((size_t)b * NS + (size_t)ch * CHS) * USTRIDE + f;
    if (f >= NF) {   // zero U pad cols (first-call garbage could be NaN)
        for (int i = 0; i < CHS; ++i) U[ubase + (size_t)i * USTRIDE] = 0;
        return;
    }
    float rx = 0.f, ry = 0.f;
    for (int c2 = 0; c2 < ch; ++c2) {
        float2 p = part[(size_t)(b * NCH + c2) * NF + f];
        rx += p.x; ry += p.y;
    }
    size_t base = ((size_t)b * NS + (size_t)ch * CHS) * 1600;
    for (int i = 0; i < CHS; ++i) {
        size_t row = base + (size_t)i * 1600;
        float2 k = uph(F[row + 513 + f]);
        float2 v = uph(F[row + 1026 + f]);
        rx += k.x * v.x - k.y * v.y;
        ry += k.x * v.y + k.y * v.x;
        float2 q = uph(F[row + f]);
        U[ubase + (size_t)i * USTRIDE] = pkc(rx * q.x + ry * q.y,
                                            ry * q.x - rx * q.y);
    }
}

// ---------------------------------------------------------------------------
extern "C" void kernel_launch(void* const* d_in, const int* in_sizes, int n_in,
                              void* d_out, int out_size, void* d_ws, size_t ws_size,
                              hipStream_t stream) {
    const float* x  = (const float*)d_in[0];
    const float* Wq = (const float*)d_in[1];
    const float* Wk = (const float*)d_in[2];
    const float* Wv = (const float*)d_in[3];
    const float* Wo = (const float*)d_in[4];
    float* out = (float*)d_out;

    char* ws = (char*)d_ws;
    unsigned short* F_all = (unsigned short*)(ws + 0);         // 8192*3200*2 = 52,428,800
    unsigned short* U     = (unsigned short*)(ws + 52428800);  // 8192*1088*2 = 17,825,792
    float2*         part  = (float2*)        (ws + 70254592);  //    525,312
    float2*         twg   = (float2*)        (ws + 70779904);  //      6,144
    unsigned short* WF    = (unsigned short*)(ws + 70786048);  // 3200*1024*2 = 6,553,600
    unsigned short* Wt    = (unsigned short*)(ws + 77339648);  // 1024*1088*2 = 2,228,224
    unsigned short* xb    = (unsigned short*)(ws + 79567872);  // 16,777,216  (end ~96.3 MB)

    convert_x<<<2048, 256, 0, stream>>>(x, xb, NTOK * D_DIM / 4);
    twiddle_init<<<3, 256, 0, stream>>>(twg);

    wf_qkv<<<dim3(512, 3), 256, 0, stream>>>(Wq, Wk, Wv, twg, WF);
    wf_zero<<<244, 256, 0, stream>>>((unsigned*)(WF + (size_t)3078 * 1024));
    wf_o<<<512, 256, 0, stream>>>(Wo, twg, Wt);

    // Fused projection+FFT: F_all[t] = (Fq | Fk | Fv) interleaved, fp16 out
    dim3 gq(NTOK / 128, NQKV / 128);
    gemm_bf16_bk64<unsigned short, true><<<gq, 256, 0, stream>>>(xb, WF, F_all, NTOK, NQKV, D_DIM);

    dim3 gs((USTRIDE + 255) / 256, NCH, NB);
    hrr_chunk_sum<<<dim3(3, NCH, NB), 256, 0, stream>>>((const unsigned*)F_all, part);
    hrr_scan_apply<<<gs, 256, 0, stream>>>((const unsigned*)F_all, part, (unsigned*)U);

    // Fused irfft+output projection (Parseval): out = U @ Wt^T
    dim3 go(NTOK / 128, D_DIM / 128);
    gemm_bf16_bk64<float, false><<<go, 256, 0, stream>>>(U, Wt, out, NTOK, D_DIM, KOUT);
}

// Round 12
// 177.710 us; speedup vs baseline: 1.3349x; 1.0763x over previous
//
#include <hip/hip_runtime.h>
#include <hip/hip_fp16.h>

#define D_DIM 1024
#define NF 513            // rfft bins = D/2+1
#define NB 4              // batch
#define NS 2048           // sequence
#define NTOK (NB * NS)    // 8192 tokens
#define NCH 32            // cumsum chunks
#define CHS (NS / NCH)    // 64 steps per chunk
#define NQKV 3072         // 3*1024 packed freq rows (real bins 0,512 share a pair)
#define KOUT 1024         // packed spectral width, no padding

typedef __attribute__((ext_vector_type(8))) short short8_t;   // 8 bf16 = 4 VGPRs
typedef __attribute__((ext_vector_type(4))) float f32x4;

__device__ inline unsigned short f2bf(float f) {
    unsigned u = __builtin_bit_cast(unsigned, f);
    u += 0x7FFFu + ((u >> 16) & 1u);   // round-to-nearest-even
    return (unsigned short)(u >> 16);
}
__device__ inline float bf2f(unsigned short h) {
    unsigned u = ((unsigned)h) << 16;
    return __builtin_bit_cast(float, u);
}
__device__ inline unsigned pkc(float re, float im) {   // packed bf16 pair
    return (unsigned)f2bf(re) | ((unsigned)f2bf(im) << 16);
}
// unpack fp16 pair
__device__ inline float2 uph(unsigned u) {
    unsigned short lo = (unsigned short)(u & 0xFFFFu), hi = (unsigned short)(u >> 16);
    return make_float2(__half2float(__builtin_bit_cast(__half, lo)),
                       __half2float(__builtin_bit_cast(__half, hi)));
}

__global__ __launch_bounds__(256) void convert_x(const float* __restrict__ src,
                                                 unsigned short* __restrict__ dst,
                                                 int n4) {
    int i = blockIdx.x * 256 + threadIdx.x;
    int stride = gridDim.x * 256;
    for (; i < n4; i += stride) {
        float4 v = reinterpret_cast<const float4*>(src)[i];
        ushort4 o;
        o.x = f2bf(v.x); o.y = f2bf(v.y); o.z = f2bf(v.z); o.w = f2bf(v.w);
        reinterpret_cast<ushort4*>(dst)[i] = o;
    }
}

__device__ inline void gload_lds16(const void* g, void* l) {
    __builtin_amdgcn_global_load_lds(
        (const __attribute__((address_space(1))) void*)g,
        (__attribute__((address_space(3))) void*)l,
        16, 0, 0);
}

// ---------------------------------------------------------------------------
// R9-proven bf16 MFMA GEMM: 128x128 tile, BK=64, 4 waves of 64x64, 2-buffer
// LDS (64 KB), counted vmcnt(8)/0, raw barriers, bank swizzle both-sides.
// ---------------------------------------------------------------------------
template <typename OutT, bool F16OUT>
__global__ __launch_bounds__(256) void gemm_bf16_bk64(const unsigned short* __restrict__ A,
                                                      const unsigned short* __restrict__ B,
                                                      OutT* __restrict__ C,
                                                      int M, int N, int K) {
    __shared__ __attribute__((aligned(16))) unsigned short ldsA[2 * 128 * 64];  // 32 KiB
    __shared__ __attribute__((aligned(16))) unsigned short ldsB[2 * 128 * 64];  // 32 KiB
    const int tid  = threadIdx.x;
    const int wave = tid >> 6;
    const int lane = tid & 63;
    const int l15  = lane & 15;
    const int q4   = (lane >> 4) & 3;
    const int h7   = l15 & 7;
    const int p0   = ((q4)     ^ h7) << 3;
    const int p1   = ((4 + q4) ^ h7) << 3;
    const int wm   = (wave >> 1) * 64;
    const int wn   = (wave & 1) * 64;
    const int bm   = blockIdx.x * 128;
    const int bn   = blockIdx.y * 128;
    const int srow = tid >> 3;
    const int scol = (((tid & 7) ^ ((tid >> 3) & 7)) << 3);
    const int NT   = K >> 6;

    const unsigned short* Asrc = A + (size_t)(bm + srow) * K + scol;
    const unsigned short* Bsrc = B + (size_t)(bn + srow) * K + scol;
    const size_t cstep = (size_t)32 * K;

    f32x4 acc[4][4];
#pragma unroll
    for (int i = 0; i < 4; ++i)
#pragma unroll
        for (int j = 0; j < 4; ++j)
            acc[i][j] = (f32x4){0.f, 0.f, 0.f, 0.f};

    auto STAGE = [&](int t, int b) {
        const int k0 = t << 6;
        unsigned short* la = &ldsA[b * 8192 + tid * 8];
        unsigned short* lb = &ldsB[b * 8192 + tid * 8];
        gload_lds16(Asrc + k0,             la);
        gload_lds16(Asrc + cstep + k0,     la + 2048);
        gload_lds16(Asrc + 2 * cstep + k0, la + 4096);
        gload_lds16(Asrc + 3 * cstep + k0, la + 6144);
        gload_lds16(Bsrc + k0,             lb);
        gload_lds16(Bsrc + cstep + k0,     lb + 2048);
        gload_lds16(Bsrc + 2 * cstep + k0, lb + 4096);
        gload_lds16(Bsrc + 3 * cstep + k0, lb + 6144);
    };

    STAGE(0, 0);

    for (int j = 0; j < NT; ++j) {
        const int buf = j & 1;
        if (j + 1 < NT) {
            STAGE(j + 1, buf ^ 1);
            asm volatile("s_waitcnt vmcnt(8)" ::: "memory");
        } else {
            asm volatile("s_waitcnt vmcnt(0)" ::: "memory");
        }
        __builtin_amdgcn_s_barrier();
        asm volatile("" ::: "memory");

        const unsigned short* la = &ldsA[buf * 8192];
        const unsigned short* lb = &ldsB[buf * 8192];

        {
            short8_t af[4], bfv[4];
#pragma unroll
            for (int mi = 0; mi < 4; ++mi)
                af[mi] = *reinterpret_cast<const short8_t*>(&la[(wm + mi * 16 + l15) * 64 + p0]);
#pragma unroll
            for (int ni = 0; ni < 4; ++ni)
                bfv[ni] = *reinterpret_cast<const short8_t*>(&lb[(wn + ni * 16 + l15) * 64 + p0]);
            __builtin_amdgcn_s_setprio(1);
#pragma unroll
            for (int mi = 0; mi < 4; ++mi)
#pragma unroll
                for (int ni = 0; ni < 4; ++ni)
                    acc[mi][ni] = __builtin_amdgcn_mfma_f32_16x16x32_bf16(af[mi], bfv[ni], acc[mi][ni], 0, 0, 0);
            __builtin_amdgcn_s_setprio(0);
        }
        {
            short8_t af[4], bfv[4];
#pragma unroll
            for (int mi = 0; mi < 4; ++mi)
                af[mi] = *reinterpret_cast<const short8_t*>(&la[(wm + mi * 16 + l15) * 64 + p1]);
#pragma unroll
            for (int ni = 0; ni < 4; ++ni)
                bfv[ni] = *reinterpret_cast<const short8_t*>(&lb[(wn + ni * 16 + l15) * 64 + p1]);
            __builtin_amdgcn_s_setprio(1);
#pragma unroll
            for (int mi = 0; mi < 4; ++mi)
#pragma unroll
                for (int ni = 0; ni < 4; ++ni)
                    acc[mi][ni] = __builtin_amdgcn_mfma_f32_16x16x32_bf16(af[mi], bfv[ni], acc[mi][ni], 0, 0, 0);
            __builtin_amdgcn_s_setprio(0);
        }

        __builtin_amdgcn_s_barrier();
        asm volatile("" ::: "memory");
    }

#pragma unroll
    for (int mi = 0; mi < 4; ++mi) {
        int rbase = bm + wm + mi * 16 + (lane >> 4) * 4;
#pragma unroll
        for (int ni = 0; ni < 4; ++ni) {
            int col = bn + wn + ni * 16 + l15;
#pragma unroll
            for (int j = 0; j < 4; ++j) {
                float v = acc[mi][ni][j];
                if constexpr (sizeof(OutT) == 4)
                    C[(size_t)(rbase + j) * N + col] = v;
                else if constexpr (F16OUT)
                    C[(size_t)(rbase + j) * N + col] =
                        __builtin_bit_cast(unsigned short, __float2half(v));
                else
                    C[(size_t)(rbase + j) * N + col] = f2bf(v);
            }
        }
    }
}

// ---------------------------------------------------------------------------
// Radix-4 1024-pt complex FFT in LDS (proven): XOR bank swizzle, digit-rev.
// ---------------------------------------------------------------------------
__device__ inline int sw(int i) { return i ^ ((i >> 4) & 15); }

__device__ inline int dr4(int n) {
    return ((n & 3) << 8) | (((n >> 2) & 3) << 6) | (((n >> 4) & 3) << 4) |
           (((n >> 6) & 3) << 2) | ((n >> 8) & 3);
}

__device__ inline float2 cmul(float2 a, float2 b) {
    return make_float2(a.x * b.x - a.y * b.y, a.x * b.y + a.y * b.x);
}

__device__ inline void fft1024_r4(float2* X, const float2* tw, int t) {
#pragma unroll
    for (int s = 0; s < 5; ++s) {
        const int L = 1 << (2 * s);
        const int r = t & (L - 1);
        const int base = ((t >> (2 * s)) << (2 * s + 2)) + r;
        float2 A  = X[sw(base)];
        float2 Bv = X[sw(base + L)];
        float2 Cv = X[sw(base + 2 * L)];
        float2 Dv = X[sw(base + 3 * L)];
        if (s != 0) {
            const int step = 1024 >> (2 * s + 2);
            Bv = cmul(Bv, tw[sw(r * step)]);
            Cv = cmul(Cv, tw[sw(2 * r * step)]);
            Dv = cmul(Dv, tw[sw(3 * r * step)]);
        }
        float2 e0 = make_float2(A.x + Cv.x, A.y + Cv.y);
        float2 e1 = make_float2(A.x - Cv.x, A.y - Cv.y);
        float2 o0 = make_float2(Bv.x + Dv.x, Bv.y + Dv.y);
        float2 o1 = make_float2(Bv.x - Dv.x, Bv.y - Dv.y);
        X[sw(base)]         = make_float2(e0.x + o0.x, e0.y + o0.y);
        X[sw(base + L)]     = make_float2(e1.x + o1.y, e1.y - o1.x);
        X[sw(base + 2 * L)] = make_float2(e0.x - o0.x, e0.y - o0.y);
        X[sw(base + 3 * L)] = make_float2(e1.x - o1.y, e1.y + o1.x);
        __syncthreads();
    }
}

__global__ __launch_bounds__(256) void twiddle_init(float2* __restrict__ twg) {
    int k = blockIdx.x * 256 + threadIdx.x;
    if (k < 768) {
        float ang = -6.283185307179586f * (float)k / 1024.0f;
        float s, c;
        sincosf(ang, &s, &c);
        twg[sw(k)] = make_float2(c, s);
    }
}

// ---------------------------------------------------------------------------
// Weight-FFT, QKV side: WF[3072][1024] bf16.  Per projection w (1024 rows):
// row 0 = Re(f=0), row 1 = Re(f=512), rows 2f/2f+1 = Re/Im(f) for f=1..511.
// Two weight columns (d0, d0+1) per block via one complex FFT + untangle.
// ---------------------------------------------------------------------------
__global__ __launch_bounds__(256) void wf_qkv(const float* __restrict__ Wq,
                                              const float* __restrict__ Wk,
                                              const float* __restrict__ Wv,
                                              const float2* __restrict__ twg,
                                              unsigned short* __restrict__ WF) {
    __shared__ __attribute__((aligned(16))) float2 X[1024];
    __shared__ __attribute__((aligned(16))) float2 twL[768];
    const int tid = threadIdx.x;
    const int w = blockIdx.y;
    const float* W = (w == 0) ? Wq : (w == 1) ? Wk : Wv;
    const int d0 = blockIdx.x * 2;
    for (int i = tid; i < 384; i += 256)
        reinterpret_cast<float4*>(twL)[i] = reinterpret_cast<const float4*>(twg)[i];
    for (int n = tid; n < 1024; n += 256) {
        float2 z = *reinterpret_cast<const float2*>(W + (size_t)n * 1024 + d0);
        X[sw(dr4(n))] = z;
    }
    __syncthreads();
    fft1024_r4(X, twL, tid);
    const int rbase = w * 1024;
    for (int f = tid; f < NF; f += 256) {
        float2 Zj = X[sw(f)];
        float2 Zm = X[sw((1024 - f) & 1023)];
        float re0 = 0.5f * (Zj.x + Zm.x), im0 = 0.5f * (Zj.y - Zm.y);
        float re1 = 0.5f * (Zj.y + Zm.y), im1 = 0.5f * (Zm.x - Zj.x);
        if (f == 0) {
            WF[(size_t)(rbase + 0) * 1024 + d0]     = f2bf(re0);
            WF[(size_t)(rbase + 0) * 1024 + d0 + 1] = f2bf(re1);
        } else if (f == 512) {
            WF[(size_t)(rbase + 1) * 1024 + d0]     = f2bf(re0);
            WF[(size_t)(rbase + 1) * 1024 + d0 + 1] = f2bf(re1);
        } else {
            WF[(size_t)(rbase + 2 * f)     * 1024 + d0]     = f2bf(re0);
            WF[(size_t)(rbase + 2 * f + 1) * 1024 + d0]     = f2bf(im0);
            WF[(size_t)(rbase + 2 * f)     * 1024 + d0 + 1] = f2bf(re1);
            WF[(size_t)(rbase + 2 * f + 1) * 1024 + d0 + 1] = f2bf(im1);
        }
    }
}

// ---------------------------------------------------------------------------
// Weight-FFT, Wo side (Parseval): Wt[1024][1024] bf16.
// col 0 = Re(0)/1024, col 1 = Re(512)/1024, cols 2f/2f+1 = 2*Re/Im(f)/1024.
// ---------------------------------------------------------------------------
__global__ __launch_bounds__(256) void wf_o(const float* __restrict__ Wo,
                                            const float2* __restrict__ twg,
                                            unsigned short* __restrict__ Wt) {
    __shared__ __attribute__((aligned(16))) float2 X[1024];
    __shared__ __attribute__((aligned(16))) float2 twL[768];
    const int tid = threadIdx.x;
    const int e0 = blockIdx.x * 2;
    for (int i = tid; i < 384; i += 256)
        reinterpret_cast<float4*>(twL)[i] = reinterpret_cast<const float4*>(twg)[i];
    const float* r0 = Wo + (size_t)e0 * 1024;
    const float* r1 = r0 + 1024;
    for (int n = tid; n < 1024; n += 256)
        X[sw(dr4(n))] = make_float2(r0[n], r1[n]);
    __syncthreads();
    fft1024_r4(X, twL, tid);
    unsigned short* o0 = Wt + (size_t)e0 * KOUT;
    unsigned short* o1 = o0 + KOUT;
    const float inv = 1.0f / 1024.0f;
    for (int f = tid; f < NF; f += 256) {
        float2 Zj = X[sw(f)];
        float2 Zm = X[sw((1024 - f) & 1023)];
        float re0 = 0.5f * (Zj.x + Zm.x), im0 = 0.5f * (Zj.y - Zm.y);
        float re1 = 0.5f * (Zj.y + Zm.y), im1 = 0.5f * (Zm.x - Zj.x);
        if (f == 0) {
            o0[0] = f2bf(re0 * inv);
            o1[0] = f2bf(re1 * inv);
        } else if (f == 512) {
            o0[1] = f2bf(re0 * inv);
            o1[1] = f2bf(re1 * inv);
        } else {
            float c = 2.0f * inv;
            o0[2 * f]     = f2bf(re0 * c);
            o0[2 * f + 1] = f2bf(im0 * c);
            o1[2 * f]     = f2bf(re1 * c);
            o1[2 * f + 1] = f2bf(im1 * c);
        }
    }
}

// ---------------------------------------------------------------------------
// Scans over F_all [8192][1536] packed fp16 u32 (Fq | Fk | Fv, 512 u32 each).
// u32 idx 0 of each projection = (Re bin0, Re bin512); idx f=1..511 = (Re,Im).
// Thread 0 handles both real bins (two scalar chains); threads 1..511 complex.
// ---------------------------------------------------------------------------
__global__ __launch_bounds__(256) void hrr_chunk_sum(const unsigned* __restrict__ F,
                                                     float2* __restrict__ part) {
    int f = blockIdx.x * 256 + threadIdx.x;   // 0..511
    int ch = blockIdx.y, b = blockIdx.z;
    size_t base = ((size_t)b * NS + (size_t)ch * CHS) * 1536;
    float2* pp = part + (size_t)(b * NCH + ch) * NF;
    if (f == 0) {
        float s0 = 0.f, s512 = 0.f;
        for (int i = 0; i < CHS; ++i) {
            size_t row = base + (size_t)i * 1536;
            float2 k = uph(F[row + 512]);
            float2 v = uph(F[row + 1024]);
            s0   += k.x * v.x;
            s512 += k.y * v.y;
        }
        pp[0]   = make_float2(s0, 0.f);
        pp[512] = make_float2(s512, 0.f);
    } else {
        float sx = 0.f, sy = 0.f;
        for (int i = 0; i < CHS; ++i) {
            size_t row = base + (size_t)i * 1536;
            float2 k = uph(F[row + 512 + f]);
            float2 v = uph(F[row + 1024 + f]);
            sx += k.x * v.x - k.y * v.y;
            sy += k.x * v.y + k.y * v.x;
        }
        pp[f] = make_float2(sx, sy);
    }
}

__global__ __launch_bounds__(256) void hrr_scan_apply(const unsigned* __restrict__ F,
                                                      const float2* __restrict__ part,
                                                      unsigned* __restrict__ U) {
    int f = blockIdx.x * 256 + threadIdx.x;   // 0..511
    int ch = blockIdx.y, b = blockIdx.z;
    size_t base  = ((size_t)b * NS + (size_t)ch * CHS) * 1536;
    size_t ubase = ((size_t)b * NS + (size_t)ch * CHS) * 512;
    const float2* pp = part + (size_t)b * NCH * NF;
    if (f == 0) {
        float r0 = 0.f, r512 = 0.f;
        for (int c2 = 0; c2 < ch; ++c2) {
            r0   += pp[(size_t)c2 * NF + 0].x;
            r512 += pp[(size_t)c2 * NF + 512].x;
        }
        for (int i = 0; i < CHS; ++i) {
            size_t row = base + (size_t)i * 1536;
            float2 k = uph(F[row + 512]);
            float2 v = uph(F[row + 1024]);
            float2 q = uph(F[row]);
            r0   += k.x * v.x;
            r512 += k.y * v.y;
            U[ubase + (size_t)i * 512] = pkc(r0 * q.x, r512 * q.y);
        }
    } else {
        float rx = 0.f, ry = 0.f;
        for (int c2 = 0; c2 < ch; ++c2) {
            float2 p = pp[(size_t)c2 * NF + f];
            rx += p.x; ry += p.y;
        }
        for (int i = 0; i < CHS; ++i) {
            size_t row = base + (size_t)i * 1536;
            float2 k = uph(F[row + 512 + f]);
            float2 v = uph(F[row + 1024 + f]);
            rx += k.x * v.x - k.y * v.y;
            ry += k.x * v.y + k.y * v.x;
            float2 q = uph(F[row + f]);
            U[ubase + (size_t)i * 512 + f] = pkc(rx * q.x + ry * q.y,
                                                 ry * q.x - rx * q.y);
        }
    }
}

// ---------------------------------------------------------------------------
extern "C" void kernel_launch(void* const* d_in, const int* in_sizes, int n_in,
                              void* d_out, int out_size, void* d_ws, size_t ws_size,
                              hipStream_t stream) {
    const float* x  = (const float*)d_in[0];
    const float* Wq = (const float*)d_in[1];
    const float* Wk = (const float*)d_in[2];
    const float* Wv = (const float*)d_in[3];
    const float* Wo = (const float*)d_in[4];
    float* out = (float*)d_out;

    char* ws = (char*)d_ws;
    unsigned short* F_all = (unsigned short*)(ws + 0);         // 8192*3072*2 = 50,331,648
    unsigned short* U     = (unsigned short*)(ws + 50331648);  // 8192*1024*2 = 16,777,216
    float2*         part  = (float2*)        (ws + 67108864);  //    525,312
    float2*         twg   = (float2*)        (ws + 67634176);  //      6,144
    unsigned short* WF    = (unsigned short*)(ws + 67640320);  // 3072*1024*2 = 6,291,456
    unsigned short* Wt    = (unsigned short*)(ws + 73931776);  // 1024*1024*2 = 2,097,152
    unsigned short* xb    = (unsigned short*)(ws + 76028928);  // 16,777,216  (end ~92.8 MB)

    convert_x<<<2048, 256, 0, stream>>>(x, xb, NTOK * D_DIM / 4);
    twiddle_init<<<3, 256, 0, stream>>>(twg);

    wf_qkv<<<dim3(512, 3), 256, 0, stream>>>(Wq, Wk, Wv, twg, WF);
    wf_o<<<512, 256, 0, stream>>>(Wo, twg, Wt);

    // Fused projection+FFT: F_all[t] = (Fq | Fk | Fv) packed fp16
    dim3 gq(NTOK / 128, NQKV / 128);
    gemm_bf16_bk64<unsigned short, true><<<gq, 256, 0, stream>>>(xb, WF, F_all, NTOK, NQKV, D_DIM);

    dim3 gs(2, NCH, NB);
    hrr_chunk_sum<<<gs, 256, 0, stream>>>((const unsigned*)F_all, part);
    hrr_scan_apply<<<gs, 256, 0, stream>>>((const unsigned*)F_all, part, (unsigned*)U);

    // Fused irfft+output projection (Parseval): out = U @ Wt^T
    dim3 go(NTOK / 128, D_DIM / 128);
    gemm_bf16_bk64<float, false><<<go, 256, 0, stream>>>(U, Wt, out, NTOK, D_DIM, KOUT);
}

// Round 13
// 175.219 us; speedup vs baseline: 1.3539x; 1.0142x over previous
//
#include <hip/hip_runtime.h>
#include <hip/hip_fp16.h>

#define D_DIM 1024
#define NF 513            // rfft bins = D/2+1
#define NB 4              // batch
#define NS 2048           // sequence
#define NTOK (NB * NS)    // 8192 tokens
#define NCH 32            // cumsum chunks
#define CHS (NS / NCH)    // 64 steps per chunk
#define NQKV 3072         // 3*1024 packed freq rows (real bins 0,512 share a pair)
#define KOUT 1024         // packed spectral width, no padding

typedef __attribute__((ext_vector_type(8))) short short8_t;   // 8 bf16 = 4 VGPRs
typedef __attribute__((ext_vector_type(4))) float f32x4;

__device__ inline unsigned short f2bf(float f) {
    unsigned u = __builtin_bit_cast(unsigned, f);
    u += 0x7FFFu + ((u >> 16) & 1u);   // round-to-nearest-even
    return (unsigned short)(u >> 16);
}
__device__ inline float bf2f(unsigned short h) {
    unsigned u = ((unsigned)h) << 16;
    return __builtin_bit_cast(float, u);
}
__device__ inline unsigned pkc(float re, float im) {   // packed bf16 pair
    return (unsigned)f2bf(re) | ((unsigned)f2bf(im) << 16);
}
// unpack fp16 pair
__device__ inline float2 uph(unsigned u) {
    unsigned short lo = (unsigned short)(u & 0xFFFFu), hi = (unsigned short)(u >> 16);
    return make_float2(__half2float(__builtin_bit_cast(__half, lo)),
                       __half2float(__builtin_bit_cast(__half, hi)));
}

__global__ __launch_bounds__(256) void convert_x(const float* __restrict__ src,
                                                 unsigned short* __restrict__ dst,
                                                 int n4) {
    int i = blockIdx.x * 256 + threadIdx.x;
    int stride = gridDim.x * 256;
    for (; i < n4; i += stride) {
        float4 v = reinterpret_cast<const float4*>(src)[i];
        ushort4 o;
        o.x = f2bf(v.x); o.y = f2bf(v.y); o.z = f2bf(v.z); o.w = f2bf(v.w);
        reinterpret_cast<ushort4*>(dst)[i] = o;
    }
}

// ---------------------------------------------------------------------------
// 64x64 LDS-tiled fp32 transpose of Wq/Wk/Wv -> WT[w][d][e] (coalesced both
// sides; pad-65 kills bank conflicts).  WT aliases the U region (dead until
// scan_apply, which runs after wf_qkv2 has consumed WT).
// ---------------------------------------------------------------------------
__global__ __launch_bounds__(256) void transpose_w(const float* __restrict__ Wq,
                                                   const float* __restrict__ Wk,
                                                   const float* __restrict__ Wv,
                                                   float* __restrict__ WT) {
    __shared__ float tile[64][65];
    const int w = blockIdx.z;
    const float* W = (w == 0) ? Wq : (w == 1) ? Wk : Wv;
    float* T = WT + (size_t)w * 1024 * 1024;
    const int bx = blockIdx.x * 64;   // input col base
    const int by = blockIdx.y * 64;   // input row base
    const int tc = threadIdx.x & 63;
    const int tr = threadIdx.x >> 6;  // 0..3
    for (int r = tr; r < 64; r += 4)
        tile[r][tc] = W[(size_t)(by + r) * 1024 + bx + tc];
    __syncthreads();
    for (int r = tr; r < 64; r += 4)
        T[(size_t)(bx + r) * 1024 + by + tc] = tile[tc][r];
}

__device__ inline void gload_lds16(const void* g, void* l) {
    __builtin_amdgcn_global_load_lds(
        (const __attribute__((address_space(1))) void*)g,
        (__attribute__((address_space(3))) void*)l,
        16, 0, 0);
}

// ---------------------------------------------------------------------------
// R9-proven bf16 MFMA GEMM: 128x128 tile, BK=64, 4 waves of 64x64, 2-buffer
// LDS (64 KB), counted vmcnt(8)/0, raw barriers, bank swizzle both-sides.
// ---------------------------------------------------------------------------
template <typename OutT, bool F16OUT>
__global__ __launch_bounds__(256) void gemm_bf16_bk64(const unsigned short* __restrict__ A,
                                                      const unsigned short* __restrict__ B,
                                                      OutT* __restrict__ C,
                                                      int M, int N, int K) {
    __shared__ __attribute__((aligned(16))) unsigned short ldsA[2 * 128 * 64];  // 32 KiB
    __shared__ __attribute__((aligned(16))) unsigned short ldsB[2 * 128 * 64];  // 32 KiB
    const int tid  = threadIdx.x;
    const int wave = tid >> 6;
    const int lane = tid & 63;
    const int l15  = lane & 15;
    const int q4   = (lane >> 4) & 3;
    const int h7   = l15 & 7;
    const int p0   = ((q4)     ^ h7) << 3;
    const int p1   = ((4 + q4) ^ h7) << 3;
    const int wm   = (wave >> 1) * 64;
    const int wn   = (wave & 1) * 64;
    const int bm   = blockIdx.x * 128;
    const int bn   = blockIdx.y * 128;
    const int srow = tid >> 3;
    const int scol = (((tid & 7) ^ ((tid >> 3) & 7)) << 3);
    const int NT   = K >> 6;

    const unsigned short* Asrc = A + (size_t)(bm + srow) * K + scol;
    const unsigned short* Bsrc = B + (size_t)(bn + srow) * K + scol;
    const size_t cstep = (size_t)32 * K;

    f32x4 acc[4][4];
#pragma unroll
    for (int i = 0; i < 4; ++i)
#pragma unroll
        for (int j = 0; j < 4; ++j)
            acc[i][j] = (f32x4){0.f, 0.f, 0.f, 0.f};

    auto STAGE = [&](int t, int b) {
        const int k0 = t << 6;
        unsigned short* la = &ldsA[b * 8192 + tid * 8];
        unsigned short* lb = &ldsB[b * 8192 + tid * 8];
        gload_lds16(Asrc + k0,             la);
        gload_lds16(Asrc + cstep + k0,     la + 2048);
        gload_lds16(Asrc + 2 * cstep + k0, la + 4096);
        gload_lds16(Asrc + 3 * cstep + k0, la + 6144);
        gload_lds16(Bsrc + k0,             lb);
        gload_lds16(Bsrc + cstep + k0,     lb + 2048);
        gload_lds16(Bsrc + 2 * cstep + k0, lb + 4096);
        gload_lds16(Bsrc + 3 * cstep + k0, lb + 6144);
    };

    STAGE(0, 0);

    for (int j = 0; j < NT; ++j) {
        const int buf = j & 1;
        if (j + 1 < NT) {
            STAGE(j + 1, buf ^ 1);
            asm volatile("s_waitcnt vmcnt(8)" ::: "memory");
        } else {
            asm volatile("s_waitcnt vmcnt(0)" ::: "memory");
        }
        __builtin_amdgcn_s_barrier();
        asm volatile("" ::: "memory");

        const unsigned short* la = &ldsA[buf * 8192];
        const unsigned short* lb = &ldsB[buf * 8192];

        {
            short8_t af[4], bfv[4];
#pragma unroll
            for (int mi = 0; mi < 4; ++mi)
                af[mi] = *reinterpret_cast<const short8_t*>(&la[(wm + mi * 16 + l15) * 64 + p0]);
#pragma unroll
            for (int ni = 0; ni < 4; ++ni)
                bfv[ni] = *reinterpret_cast<const short8_t*>(&lb[(wn + ni * 16 + l15) * 64 + p0]);
            __builtin_amdgcn_s_setprio(1);
#pragma unroll
            for (int mi = 0; mi < 4; ++mi)
#pragma unroll
                for (int ni = 0; ni < 4; ++ni)
                    acc[mi][ni] = __builtin_amdgcn_mfma_f32_16x16x32_bf16(af[mi], bfv[ni], acc[mi][ni], 0, 0, 0);
            __builtin_amdgcn_s_setprio(0);
        }
        {
            short8_t af[4], bfv[4];
#pragma unroll
            for (int mi = 0; mi < 4; ++mi)
                af[mi] = *reinterpret_cast<const short8_t*>(&la[(wm + mi * 16 + l15) * 64 + p1]);
#pragma unroll
            for (int ni = 0; ni < 4; ++ni)
                bfv[ni] = *reinterpret_cast<const short8_t*>(&lb[(wn + ni * 16 + l15) * 64 + p1]);
            __builtin_amdgcn_s_setprio(1);
#pragma unroll
            for (int mi = 0; mi < 4; ++mi)
#pragma unroll
                for (int ni = 0; ni < 4; ++ni)
                    acc[mi][ni] = __builtin_amdgcn_mfma_f32_16x16x32_bf16(af[mi], bfv[ni], acc[mi][ni], 0, 0, 0);
            __builtin_amdgcn_s_setprio(0);
        }

        __builtin_amdgcn_s_barrier();
        asm volatile("" ::: "memory");
    }

#pragma unroll
    for (int mi = 0; mi < 4; ++mi) {
        int rbase = bm + wm + mi * 16 + (lane >> 4) * 4;
#pragma unroll
        for (int ni = 0; ni < 4; ++ni) {
            int col = bn + wn + ni * 16 + l15;
#pragma unroll
            for (int j = 0; j < 4; ++j) {
                float v = acc[mi][ni][j];
                if constexpr (sizeof(OutT) == 4)
                    C[(size_t)(rbase + j) * N + col] = v;
                else if constexpr (F16OUT)
                    C[(size_t)(rbase + j) * N + col] =
                        __builtin_bit_cast(unsigned short, __float2half(v));
                else
                    C[(size_t)(rbase + j) * N + col] = f2bf(v);
            }
        }
    }
}

// ---------------------------------------------------------------------------
// Radix-4 1024-pt complex FFT in LDS (proven): XOR bank swizzle, digit-rev.
// ---------------------------------------------------------------------------
__device__ inline int sw(int i) { return i ^ ((i >> 4) & 15); }

__device__ inline int dr4(int n) {
    return ((n & 3) << 8) | (((n >> 2) & 3) << 6) | (((n >> 4) & 3) << 4) |
           (((n >> 6) & 3) << 2) | ((n >> 8) & 3);
}

__device__ inline float2 cmul(float2 a, float2 b) {
    return make_float2(a.x * b.x - a.y * b.y, a.x * b.y + a.y * b.x);
}

__device__ inline void fft1024_r4(float2* X, const float2* tw, int t) {
#pragma unroll
    for (int s = 0; s < 5; ++s) {
        const int L = 1 << (2 * s);
        const int r = t & (L - 1);
        const int base = ((t >> (2 * s)) << (2 * s + 2)) + r;
        float2 A  = X[sw(base)];
        float2 Bv = X[sw(base + L)];
        float2 Cv = X[sw(base + 2 * L)];
        float2 Dv = X[sw(base + 3 * L)];
        if (s != 0) {
            const int step = 1024 >> (2 * s + 2);
            Bv = cmul(Bv, tw[sw(r * step)]);
            Cv = cmul(Cv, tw[sw(2 * r * step)]);
            Dv = cmul(Dv, tw[sw(3 * r * step)]);
        }
        float2 e0 = make_float2(A.x + Cv.x, A.y + Cv.y);
        float2 e1 = make_float2(A.x - Cv.x, A.y - Cv.y);
        float2 o0 = make_float2(Bv.x + Dv.x, Bv.y + Dv.y);
        float2 o1 = make_float2(Bv.x - Dv.x, Bv.y - Dv.y);
        X[sw(base)]         = make_float2(e0.x + o0.x, e0.y + o0.y);
        X[sw(base + L)]     = make_float2(e1.x + o1.y, e1.y - o1.x);
        X[sw(base + 2 * L)] = make_float2(e0.x - o0.x, e0.y - o0.y);
        X[sw(base + 3 * L)] = make_float2(e1.x - o1.y, e1.y + o1.x);
        __syncthreads();
    }
}

__global__ __launch_bounds__(256) void twiddle_init(float2* __restrict__ twg) {
    int k = blockIdx.x * 256 + threadIdx.x;
    if (k < 768) {
        float ang = -6.283185307179586f * (float)k / 1024.0f;
        float s, c;
        sincosf(ang, &s, &c);
        twg[sw(k)] = make_float2(c, s);
    }
}

// ---------------------------------------------------------------------------
// Weight-FFT, QKV side (v2: reads TRANSPOSED weights -> coalesced rows).
// WF[3072][1024] bf16.  Per projection w (1024 rows): row 0 = Re(f=0),
// row 1 = Re(f=512), rows 2f/2f+1 = Re/Im(f) for f=1..511.
// Block handles WT rows d0, d0+1 via one complex FFT + untangle.
// ---------------------------------------------------------------------------
__global__ __launch_bounds__(256) void wf_qkv2(const float* __restrict__ WT,
                                               const float2* __restrict__ twg,
                                               unsigned short* __restrict__ WF) {
    __shared__ __attribute__((aligned(16))) float2 X[1024];
    __shared__ __attribute__((aligned(16))) float2 twL[768];
    const int tid = threadIdx.x;
    const int w = blockIdx.y;
    const int d0 = blockIdx.x * 2;
    for (int i = tid; i < 384; i += 256)
        reinterpret_cast<float4*>(twL)[i] = reinterpret_cast<const float4*>(twg)[i];
    const float* r0 = WT + (size_t)w * 1048576 + (size_t)d0 * 1024;
    const float* r1 = r0 + 1024;
    for (int n = tid; n < 1024; n += 256)
        X[sw(dr4(n))] = make_float2(r0[n], r1[n]);
    __syncthreads();
    fft1024_r4(X, twL, tid);
    const int rbase = w * 1024;
    for (int f = tid; f < NF; f += 256) {
        float2 Zj = X[sw(f)];
        float2 Zm = X[sw((1024 - f) & 1023)];
        float re0 = 0.5f * (Zj.x + Zm.x), im0 = 0.5f * (Zj.y - Zm.y);
        float re1 = 0.5f * (Zj.y + Zm.y), im1 = 0.5f * (Zm.x - Zj.x);
        if (f == 0) {
            WF[(size_t)(rbase + 0) * 1024 + d0]     = f2bf(re0);
            WF[(size_t)(rbase + 0) * 1024 + d0 + 1] = f2bf(re1);
        } else if (f == 512) {
            WF[(size_t)(rbase + 1) * 1024 + d0]     = f2bf(re0);
            WF[(size_t)(rbase + 1) * 1024 + d0 + 1] = f2bf(re1);
        } else {
            WF[(size_t)(rbase + 2 * f)     * 1024 + d0]     = f2bf(re0);
            WF[(size_t)(rbase + 2 * f + 1) * 1024 + d0]     = f2bf(im0);
            WF[(size_t)(rbase + 2 * f)     * 1024 + d0 + 1] = f2bf(re1);
            WF[(size_t)(rbase + 2 * f + 1) * 1024 + d0 + 1] = f2bf(im1);
        }
    }
}

// ---------------------------------------------------------------------------
// Weight-FFT, Wo side (Parseval): Wt[1024][1024] bf16.
// col 0 = Re(0)/1024, col 1 = Re(512)/1024, cols 2f/2f+1 = 2*Re/Im(f)/1024.
// ---------------------------------------------------------------------------
__global__ __launch_bounds__(256) void wf_o(const float* __restrict__ Wo,
                                            const float2* __restrict__ twg,
                                            unsigned short* __restrict__ Wt) {
    __shared__ __attribute__((aligned(16))) float2 X[1024];
    __shared__ __attribute__((aligned(16))) float2 twL[768];
    const int tid = threadIdx.x;
    const int e0 = blockIdx.x * 2;
    for (int i = tid; i < 384; i += 256)
        reinterpret_cast<float4*>(twL)[i] = reinterpret_cast<const float4*>(twg)[i];
    const float* r0 = Wo + (size_t)e0 * 1024;
    const float* r1 = r0 + 1024;
    for (int n = tid; n < 1024; n += 256)
        X[sw(dr4(n))] = make_float2(r0[n], r1[n]);
    __syncthreads();
    fft1024_r4(X, twL, tid);
    unsigned short* o0 = Wt + (size_t)e0 * KOUT;
    unsigned short* o1 = o0 + KOUT;
    const float inv = 1.0f / 1024.0f;
    for (int f = tid; f < NF; f += 256) {
        float2 Zj = X[sw(f)];
        float2 Zm = X[sw((1024 - f) & 1023)];
        float re0 = 0.5f * (Zj.x + Zm.x), im0 = 0.5f * (Zj.y - Zm.y);
        float re1 = 0.5f * (Zj.y + Zm.y), im1 = 0.5f * (Zm.x - Zj.x);
        if (f == 0) {
            o0[0] = f2bf(re0 * inv);
            o1[0] = f2bf(re1 * inv);
        } else if (f == 512) {
            o0[1] = f2bf(re0 * inv);
            o1[1] = f2bf(re1 * inv);
        } else {
            float c = 2.0f * inv;
            o0[2 * f]     = f2bf(re0 * c);
            o0[2 * f + 1] = f2bf(im0 * c);
            o1[2 * f]     = f2bf(re1 * c);
            o1[2 * f + 1] = f2bf(im1 * c);
        }
    }
}

// ---------------------------------------------------------------------------
// Scans over F_all [8192][1536] packed fp16 u32 (Fq | Fk | Fv, 512 u32 each).
// u32 idx 0 of each projection = (Re bin0, Re bin512); idx f=1..511 = (Re,Im).
// ---------------------------------------------------------------------------
__global__ __launch_bounds__(256) void hrr_chunk_sum(const unsigned* __restrict__ F,
                                                     float2* __restrict__ part) {
    int f = blockIdx.x * 256 + threadIdx.x;   // 0..511
    int ch = blockIdx.y, b = blockIdx.z;
    size_t base = ((size_t)b * NS + (size_t)ch * CHS) * 1536;
    float2* pp = part + (size_t)(b * NCH + ch) * NF;
    if (f == 0) {
        float s0 = 0.f, s512 = 0.f;
        for (int i = 0; i < CHS; ++i) {
            size_t row = base + (size_t)i * 1536;
            float2 k = uph(F[row + 512]);
            float2 v = uph(F[row + 1024]);
            s0   += k.x * v.x;
            s512 += k.y * v.y;
        }
        pp[0]   = make_float2(s0, 0.f);
        pp[512] = make_float2(s512, 0.f);
    } else {
        float sx = 0.f, sy = 0.f;
        for (int i = 0; i < CHS; ++i) {
            size_t row = base + (size_t)i * 1536;
            float2 k = uph(F[row + 512 + f]);
            float2 v = uph(F[row + 1024 + f]);
            sx += k.x * v.x - k.y * v.y;
            sy += k.x * v.y + k.y * v.x;
        }
        pp[f] = make_float2(sx, sy);
    }
}

__global__ __launch_bounds__(256) void hrr_scan_apply(const unsigned* __restrict__ F,
                                                      const float2* __restrict__ part,
                                                      unsigned* __restrict__ U) {
    int f = blockIdx.x * 256 + threadIdx.x;   // 0..511
    int ch = blockIdx.y, b = blockIdx.z;
    size_t base  = ((size_t)b * NS + (size_t)ch * CHS) * 1536;
    size_t ubase = ((size_t)b * NS + (size_t)ch * CHS) * 512;
    const float2* pp = part + (size_t)b * NCH * NF;
    if (f == 0) {
        float r0 = 0.f, r512 = 0.f;
        for (int c2 = 0; c2 < ch; ++c2) {
            r0   += pp[(size_t)c2 * NF + 0].x;
            r512 += pp[(size_t)c2 * NF + 512].x;
        }
        for (int i = 0; i < CHS; ++i) {
            size_t row = base + (size_t)i * 1536;
            float2 k = uph(F[row + 512]);
            float2 v = uph(F[row + 1024]);
            float2 q = uph(F[row]);
            r0   += k.x * v.x;
            r512 += k.y * v.y;
            U[ubase + (size_t)i * 512] = pkc(r0 * q.x, r512 * q.y);
        }
    } else {
        float rx = 0.f, ry = 0.f;
        for (int c2 = 0; c2 < ch; ++c2) {
            float2 p = pp[(size_t)c2 * NF + f];
            rx += p.x; ry += p.y;
        }
        for (int i = 0; i < CHS; ++i) {
            size_t row = base + (size_t)i * 1536;
            float2 k = uph(F[row + 512 + f]);
            float2 v = uph(F[row + 1024 + f]);
            rx += k.x * v.x - k.y * v.y;
            ry += k.x * v.y + k.y * v.x;
            float2 q = uph(F[row + f]);
            U[ubase + (size_t)i * 512 + f] = pkc(rx * q.x + ry * q.y,
                                                 ry * q.x - rx * q.y);
        }
    }
}

// ---------------------------------------------------------------------------
extern "C" void kernel_launch(void* const* d_in, const int* in_sizes, int n_in,
                              void* d_out, int out_size, void* d_ws, size_t ws_size,
                              hipStream_t stream) {
    const float* x  = (const float*)d_in[0];
    const float* Wq = (const float*)d_in[1];
    const float* Wk = (const float*)d_in[2];
    const float* Wv = (const float*)d_in[3];
    const float* Wo = (const float*)d_in[4];
    float* out = (float*)d_out;

    char* ws = (char*)d_ws;
    unsigned short* F_all = (unsigned short*)(ws + 0);         // 8192*3072*2 = 50,331,648
    unsigned short* U     = (unsigned short*)(ws + 50331648);  // 8192*1024*2 = 16,777,216
    float2*         part  = (float2*)        (ws + 67108864);  //    525,312
    float2*         twg   = (float2*)        (ws + 67634176);  //      6,144
    unsigned short* WF    = (unsigned short*)(ws + 67640320);  // 3072*1024*2 = 6,291,456
    unsigned short* Wt    = (unsigned short*)(ws + 73931776);  // 1024*1024*2 = 2,097,152
    unsigned short* xb    = (unsigned short*)(ws + 76028928);  // 16,777,216  (end ~92.8 MB)
    // WT (12.6 MB fp32) aliases U region: written by transpose_w, consumed by
    // wf_qkv2, then U overwrites it later via hrr_scan_apply.  Need 12.6 MB but
    // U region is 16.8 MB -> fits.
    float* WT = (float*)U;

    convert_x<<<2048, 256, 0, stream>>>(x, xb, NTOK * D_DIM / 4);
    twiddle_init<<<3, 256, 0, stream>>>(twg);

    transpose_w<<<dim3(16, 16, 3), 256, 0, stream>>>(Wq, Wk, Wv, WT);
    wf_qkv2<<<dim3(512, 3), 256, 0, stream>>>(WT, twg, WF);
    wf_o<<<512, 256, 0, stream>>>(Wo, twg, Wt);

    // Fused projection+FFT: F_all[t] = (Fq | Fk | Fv) packed fp16
    dim3 gq(NTOK / 128, NQKV / 128);
    gemm_bf16_bk64<unsigned short, true><<<gq, 256, 0, stream>>>(xb, WF, F_all, NTOK, NQKV, D_DIM);

    dim3 gs(2, NCH, NB);
    hrr_chunk_sum<<<gs, 256, 0, stream>>>((const unsigned*)F_all, part);
    hrr_scan_apply<<<gs, 256, 0, stream>>>((const unsigned*)F_all, part, (unsigned*)U);

    // Fused irfft+output projection (Parseval): out = U @ Wt^T
    dim3 go(NTOK / 128, D_DIM / 128);
    gemm_bf16_bk64<float, false><<<go, 256, 0, stream>>>(U, Wt, out, NTOK, D_DIM, KOUT);
}